// Round 2
// baseline (552.296 us; speedup 1.0000x reference)
//
#include <hip/hip_runtime.h>

typedef _Float16 half8  __attribute__((ext_vector_type(8)));
typedef _Float16 half4_t __attribute__((ext_vector_type(4)));
typedef __fp16   fp16x2 __attribute__((ext_vector_type(2)));
typedef float    f32x4  __attribute__((ext_vector_type(4)));

union I4H8 { int i[4]; half8 h; };
union PK   { fp16x2 h; int i; };

// element-level swizzled indices (halves). XOR bits are multiples of 8 halves
// (16 B), so 16B ds_read_b128 chunks stay contiguous.
__device__ __forceinline__ int tokIdx(int r, int c) { return r*256 + (c ^ ((r & 7) << 3)); }
__device__ __forceinline__ int ksIdx (int r, int c) { return r*32  + (c ^ (((r >> 1) & 3) << 3)); }
__device__ __forceinline__ int vtIdx (int d, int t) { return d*64  + (t ^ ((d & 7) << 3)); }

// ---- fp32 -> fp16 weight conversion into workspace ----
// layout: w16[0 .. 768*256)              = w_qkv  (row-major [768][256])
//         w16[768*256 .. 768*256+65536)  = w_proj (row-major [256][256])
__global__ void __launch_bounds__(256)
wconv_kernel(const float* __restrict__ wq, const float* __restrict__ wp,
             _Float16* __restrict__ o)
{
  const int i = blockIdx.x * 256 + threadIdx.x;   // grid covers exactly 262144
  if (i < 768*256) o[i] = (_Float16)wq[i];
  else             o[i] = (_Float16)wp[i - 768*256];
}

__global__ void __launch_bounds__(256, 2)
attn_kernel(const float* __restrict__ x,
            const float* __restrict__ b_qkv,
            const float* __restrict__ b_proj,
            const _Float16* __restrict__ w16,
            float* __restrict__ out)
{
  __shared__ __align__(16) _Float16 tok[64*256];   // 32 KB; reused as attn-out for proj
  __shared__ __align__(16) _Float16 scr[4][4096];  // per-wave: Ks[64][32] | Vt[32][64]

  const int tid  = threadIdx.x;
  const int lane = tid & 63;
  const int w    = tid >> 6;        // wave 0..3
  const int l15  = lane & 15;
  const int g    = lane >> 4;       // lane group 0..3

  const int wid = blockIdx.x;
  const int b   = wid / (24*24);
  const int wh  = (wid / 24) % 24;
  const int ww  = wid % 24;
  const long long base = (((long long)b*192 + wh*8)*192 + ww*8)*256;

  // ---------------- stage tokens -> LDS fp16 (swizzled) ----------------
#pragma unroll
  for (int i = 0; i < 16; ++i) {
    const int tk = w*16 + i;
    const float4 v = *(const float4*)(x + base + ((tk >> 3)*192 + (tk & 7))*256 + lane*4);
    half4_t h;
    h[0] = (_Float16)v.x; h[1] = (_Float16)v.y;
    h[2] = (_Float16)v.z; h[3] = (_Float16)v.w;
    *(half4_t*)(tok + tk*256 + ((lane*4) ^ ((tk & 7) << 3))) = h;
  }
  __syncthreads();

  const _Float16* wqkv16  = w16;              // [768][256]
  const _Float16* wproj16 = w16 + 768*256;    // [256][256]
  _Float16* Ks = &scr[w][0];                  // [64 key][32 d]
  _Float16* Vt = &scr[w][2048];               // [32 d][64 key]

  // cross-lane map: element held at lane (l15 | g'<<4), g' = 2*(g&1)+bit
  const int srcA  = l15 | ((2*(g & 1)    ) << 4);
  const int srcB  = l15 | ((2*(g & 1) + 1) << 4);
  const bool misel = (g >> 1) != 0;

  f32x4 oh[2][2][4];   // [head][mi_d][ni_q] attention outputs (O^T fragments)

#pragma unroll
  for (int hi = 0; hi < 2; ++hi) {
    const int hd = 2*w + hi;

    // ---------------- Q^T = Wq * X^T   (M=32 d, N=64 q, K=256) ----------------
    f32x4 qa[2][4];
#pragma unroll
    for (int mi = 0; mi < 2; ++mi)
#pragma unroll
      for (int ni = 0; ni < 4; ++ni) qa[mi][ni] = (f32x4)0.0f;

#pragma unroll
    for (int kk = 0; kk < 8; ++kk) {
      half8 aw[2], bt[4];
#pragma unroll
      for (int mi = 0; mi < 2; ++mi)
        aw[mi] = *(const half8*)(wqkv16 + (hd*32 + mi*16 + l15)*256 + kk*32 + g*8);
#pragma unroll
      for (int ni = 0; ni < 4; ++ni)
        bt[ni] = *(const half8*)(tok + tokIdx(ni*16 + l15, kk*32 + g*8));
#pragma unroll
      for (int mi = 0; mi < 2; ++mi)
#pragma unroll
        for (int ni = 0; ni < 4; ++ni)
          qa[mi][ni] = __builtin_amdgcn_mfma_f32_16x16x32_f16(aw[mi], bt[ni], qa[mi][ni], 0, 0, 0);
    }

    // bias (indexed by row d = mi*16 + g*4 + r) then pack to fp16 pairs (r0,r1),(r2,r3)
    int qtp[2][4][2];
#pragma unroll
    for (int mi = 0; mi < 2; ++mi) {
      float bq[4];
#pragma unroll
      for (int r = 0; r < 4; ++r) bq[r] = b_qkv[hd*32 + mi*16 + g*4 + r];
#pragma unroll
      for (int ni = 0; ni < 4; ++ni) {
        PK u0, u1;
        u0.h = __builtin_amdgcn_cvt_pkrtz(qa[mi][ni][0] + bq[0], qa[mi][ni][1] + bq[1]);
        u1.h = __builtin_amdgcn_cvt_pkrtz(qa[mi][ni][2] + bq[2], qa[mi][ni][3] + bq[3]);
        qtp[mi][ni][0] = u0.i;
        qtp[mi][ni][1] = u1.i;
      }
    }

    // ---------------- K|V = X * W^T  (M=64 tok, N=64 [k|v], K=256) ----------------
    f32x4 kv[4][4];
#pragma unroll
    for (int mi = 0; mi < 4; ++mi)
#pragma unroll
      for (int ni = 0; ni < 4; ++ni) kv[mi][ni] = (f32x4)0.0f;

#pragma unroll
    for (int kk = 0; kk < 8; ++kk) {
      half8 at[4], bw[4];
#pragma unroll
      for (int mi = 0; mi < 4; ++mi)
        at[mi] = *(const half8*)(tok + tokIdx(mi*16 + l15, kk*32 + g*8));
#pragma unroll
      for (int ni = 0; ni < 4; ++ni) {
        const int row = (ni < 2) ? (256 + hd*32 + ni*16 + l15)
                                 : (512 + hd*32 + (ni - 2)*16 + l15);
        bw[ni] = *(const half8*)(wqkv16 + row*256 + kk*32 + g*8);
      }
#pragma unroll
      for (int mi = 0; mi < 4; ++mi)
#pragma unroll
        for (int ni = 0; ni < 4; ++ni)
          kv[mi][ni] = __builtin_amdgcn_mfma_f32_16x16x32_f16(at[mi], bw[ni], kv[mi][ni], 0, 0, 0);
    }

    // bias (col-indexed) + store K to Ks[key][d], V transposed to Vt[d][key]
#pragma unroll
    for (int ni = 0; ni < 4; ++ni) {
      const float bb = b_qkv[(ni < 2 ? 256 + hd*32 + ni*16 : 512 + hd*32 + (ni - 2)*16) + l15];
#pragma unroll
      for (int mi = 0; mi < 4; ++mi)
#pragma unroll
        for (int r = 0; r < 4; ++r) {
          const float vv = kv[mi][ni][r] + bb;
          const int trow = mi*16 + g*4 + r;
          if (ni < 2) Ks[ksIdx(trow, ni*16 + l15)]            = (_Float16)vv;
          else        Vt[vtIdx((ni - 2)*16 + l15, trow)]      = (_Float16)vv;
        }
    }

    // ---------------- S^T = K * Q^T   (M=64 key, N=64 q, K=32) ----------------
    half8 ka[4];
#pragma unroll
    for (int mi = 0; mi < 4; ++mi)
      ka[mi] = *(const half8*)(Ks + ksIdx(mi*16 + l15, g*8));

    f32x4 s[4][4];
#pragma unroll
    for (int mi = 0; mi < 4; ++mi)
#pragma unroll
      for (int ni = 0; ni < 4; ++ni) s[mi][ni] = (f32x4)0.0f;

#pragma unroll
    for (int ni = 0; ni < 4; ++ni) {
      const int t0 = __shfl(qtp[0][ni][0], srcA, 64);
      const int t1 = __shfl(qtp[1][ni][0], srcA, 64);
      const int t2 = __shfl(qtp[0][ni][1], srcA, 64);
      const int t3 = __shfl(qtp[1][ni][1], srcA, 64);
      const int t4 = __shfl(qtp[0][ni][0], srcB, 64);
      const int t5 = __shfl(qtp[1][ni][0], srcB, 64);
      const int t6 = __shfl(qtp[0][ni][1], srcB, 64);
      const int t7 = __shfl(qtp[1][ni][1], srcB, 64);
      I4H8 u;
      u.i[0] = misel ? t1 : t0;
      u.i[1] = misel ? t3 : t2;
      u.i[2] = misel ? t5 : t4;
      u.i[3] = misel ? t7 : t6;
#pragma unroll
      for (int mi = 0; mi < 4; ++mi)
        s[mi][ni] = __builtin_amdgcn_mfma_f32_16x16x32_f16(ka[mi], u.h, s[mi][ni], 0, 0, 0);
    }

    // ---------------- softmax over keys (rows of S^T), per column q ----------------
    const float alpha = 0.17677669529663687f;   // 1/sqrt(32)
    int pk[4][4][2];
    float rv[4];
#pragma unroll
    for (int ni = 0; ni < 4; ++ni) {
      float m = s[0][ni][0];
#pragma unroll
      for (int mi = 0; mi < 4; ++mi)
#pragma unroll
        for (int r = 0; r < 4; ++r) m = fmaxf(m, s[mi][ni][r]);
      m = fmaxf(m, __shfl_xor(m, 16, 64));
      m = fmaxf(m, __shfl_xor(m, 32, 64));
      float sum = 0.0f;
#pragma unroll
      for (int mi = 0; mi < 4; ++mi)
#pragma unroll
        for (int r = 0; r < 4; ++r) {
          const float e = __expf((s[mi][ni][r] - m) * alpha);
          sum += e;
          s[mi][ni][r] = e;
        }
      sum += __shfl_xor(sum, 16, 64);
      sum += __shfl_xor(sum, 32, 64);
      rv[ni] = 1.0f / sum;
#pragma unroll
      for (int mi = 0; mi < 4; ++mi) {
        PK u0, u1;
        u0.h = __builtin_amdgcn_cvt_pkrtz(s[mi][ni][0], s[mi][ni][1]);
        u1.h = __builtin_amdgcn_cvt_pkrtz(s[mi][ni][2], s[mi][ni][3]);
        pk[mi][ni][0] = u0.i;
        pk[mi][ni][1] = u1.i;
      }
    }

    // ---------------- O^T = V^T * P^T   (M=32 d, N=64 q, K=64) ----------------
#pragma unroll
    for (int mi = 0; mi < 2; ++mi)
#pragma unroll
      for (int ni = 0; ni < 4; ++ni) oh[hi][mi][ni] = (f32x4)0.0f;

#pragma unroll
    for (int kk = 0; kk < 2; ++kk) {
      half8 va[2];
#pragma unroll
      for (int mi = 0; mi < 2; ++mi)
        va[mi] = *(const half8*)(Vt + vtIdx(mi*16 + l15, kk*32 + g*8));
#pragma unroll
      for (int ni = 0; ni < 4; ++ni) {
        const int t0 = __shfl(pk[2*kk    ][ni][0], srcA, 64);
        const int t1 = __shfl(pk[2*kk + 1][ni][0], srcA, 64);
        const int t2 = __shfl(pk[2*kk    ][ni][1], srcA, 64);
        const int t3 = __shfl(pk[2*kk + 1][ni][1], srcB ? srcA : srcA, 64);
        const int t4 = __shfl(pk[2*kk    ][ni][0], srcB, 64);
        const int t5 = __shfl(pk[2*kk + 1][ni][0], srcB, 64);
        const int t6 = __shfl(pk[2*kk    ][ni][1], srcB, 64);
        const int t7 = __shfl(pk[2*kk + 1][ni][1], srcB, 64);
        I4H8 u;
        u.i[0] = misel ? t1 : t0;
        u.i[1] = misel ? t3 : t2;
        u.i[2] = misel ? t5 : t4;
        u.i[3] = misel ? t7 : t6;
#pragma unroll
        for (int mi = 0; mi < 2; ++mi)
          oh[hi][mi][ni] = __builtin_amdgcn_mfma_f32_16x16x32_f16(va[mi], u.h, oh[hi][mi][ni], 0, 0, 0);
      }
    }
    // deferred softmax normalization (per column q)
#pragma unroll
    for (int mi = 0; mi < 2; ++mi)
#pragma unroll
      for (int ni = 0; ni < 4; ++ni)
#pragma unroll
        for (int r = 0; r < 4; ++r) oh[hi][mi][ni][r] *= rv[ni];
  }

  __syncthreads();   // all waves done reading tok (and their scratch)

  // ---------------- write attention output into LDS (aliases tok) ----------------
#pragma unroll
  for (int hi = 0; hi < 2; ++hi) {
    const int hd = 2*w + hi;
#pragma unroll
    for (int mi = 0; mi < 2; ++mi)
#pragma unroll
      for (int ni = 0; ni < 4; ++ni)
#pragma unroll
        for (int r = 0; r < 4; ++r)
          tok[tokIdx(ni*16 + l15, hd*32 + mi*16 + g*4 + r)] = (_Float16)oh[hi][mi][ni][r];
  }
  __syncthreads();

  // ---------------- proj: out = AO * Wp^T + bp  (M=64, N=64/wave, K=256) ----------------
  f32x4 pa[4][4];
#pragma unroll
  for (int mi = 0; mi < 4; ++mi)
#pragma unroll
    for (int ni = 0; ni < 4; ++ni) pa[mi][ni] = (f32x4)0.0f;

#pragma unroll
  for (int kk = 0; kk < 8; ++kk) {
    half8 af[4], bf[4];
#pragma unroll
    for (int mi = 0; mi < 4; ++mi)
      af[mi] = *(const half8*)(tok + tokIdx(mi*16 + l15, kk*32 + g*8));
#pragma unroll
    for (int ni = 0; ni < 4; ++ni)
      bf[ni] = *(const half8*)(wproj16 + (w*64 + ni*16 + l15)*256 + kk*32 + g*8);
#pragma unroll
    for (int mi = 0; mi < 4; ++mi)
#pragma unroll
      for (int ni = 0; ni < 4; ++ni)
        pa[mi][ni] = __builtin_amdgcn_mfma_f32_16x16x32_f16(af[mi], bf[ni], pa[mi][ni], 0, 0, 0);
  }

#pragma unroll
  for (int ni = 0; ni < 4; ++ni) {
    const float bb = b_proj[w*64 + ni*16 + l15];
#pragma unroll
    for (int mi = 0; mi < 4; ++mi)
#pragma unroll
      for (int r = 0; r < 4; ++r) {
        const int t = mi*16 + g*4 + r;
        out[base + ((t >> 3)*192 + (t & 7))*256 + w*64 + ni*16 + l15] = pa[mi][ni][r] + bb;
      }
  }
}

extern "C" void kernel_launch(void* const* d_in, const int* in_sizes, int n_in,
                              void* d_out, int out_size, void* d_ws, size_t ws_size,
                              hipStream_t stream) {
  const float* x      = (const float*)d_in[0];
  const float* w_qkv  = (const float*)d_in[1];
  const float* b_qkv  = (const float*)d_in[2];
  const float* w_proj = (const float*)d_in[3];
  const float* b_proj = (const float*)d_in[4];
  float* out = (float*)d_out;
  _Float16* w16 = (_Float16*)d_ws;   // 524288 B used

  wconv_kernel<<<1024, 256, 0, stream>>>(w_qkv, w_proj, w16);
  attn_kernel<<<4608, 256, 0, stream>>>(x, b_qkv, b_proj, w16, out);
}